// Round 5
// baseline (1575.922 us; speedup 1.0000x reference)
//
#include <hip/hip_runtime.h>

// SNN forward: T=20, B=65536, F=16; layers 16->128->128->64->10, LIF beta=0.9,
// thr=1.0, reset-subtract. Bit-exact semantics (verified r3/r4 absmax=0):
// ascending-k fmaf dot chains; spikes as float {0.0,1.0} multiplicands
// (fmaf(1,w,a)=a+w, fmaf(0,w,a)=a exactly); uncontracted ((0.9*m)+c)-r LIF.
// r5: dense fma pipeline, spike float4s through per-wave LDS broadcast reads
// (uniform addr = conflict-free). No scalar branches in hot loop (r4's SALU
// wall), no mask arrays (r4's spill wall). S=8 batch/wave amortizes weights.

namespace {
constexpr int kB = 65536;
constexpr int kT = 20;
constexpr int S = 8;        // batch elements per wave
constexpr int WAVES = 12;   // waves per block (768 threads)
constexpr int NGRP = kB / S;          // 8192 batch groups
constexpr int TOTW = 256 * WAVES;     // 3072 waves in grid
}

__device__ __forceinline__ float fma4(const float4 s, const float4 wv, float acc) {
  acc = fmaf(s.x, wv.x, acc);
  acc = fmaf(s.y, wv.y, acc);
  acc = fmaf(s.z, wv.z, acc);
  acc = fmaf(s.w, wv.w, acc);
  return acc;
}

__global__ __launch_bounds__(768, 3) void snn_fwd(
    const float* __restrict__ x,
    const float* __restrict__ gw1,
    const float* __restrict__ gw2,
    const float* __restrict__ gw3,
    const float* __restrict__ gw4,
    float* __restrict__ out)
{
#pragma clang fp contract(off)
  // Weights: chunk-XOR swizzle so per-lane row reads (stride 128B for w2/w3)
  // are conflict-free (verified r3/r4). Spike buffers: per-wave, broadcast-read.
  __shared__ __align__(16) float w1s[128 * 16];    //  8 KB
  __shared__ __align__(16) float w2s[128 * 128];   // 64 KB
  __shared__ __align__(16) float w3s[64 * 128];    // 32 KB
  __shared__ __align__(16) float w4s[10 * 64];     // 2.5 KB
  __shared__ __align__(16) float spkf[WAVES][S][128];  // 48 KB

  const int tid = threadIdx.x;

  for (int i = tid; i < 128 * 16; i += 768) {
    int j = i >> 4, k = i & 15;
    w1s[(j << 4) + ((((k >> 2) ^ j) & 3) << 2) + (k & 3)] = gw1[i];
  }
  for (int i = tid; i < 128 * 128; i += 768) {
    int j = i >> 7, k = i & 127;
    w2s[(j << 7) + ((((k >> 2) ^ j) & 31) << 2) + (k & 3)] = gw2[i];
  }
  for (int i = tid; i < 64 * 128; i += 768) {
    int j = i >> 7, k = i & 127;
    w3s[(j << 7) + ((((k >> 2) ^ j) & 31) << 2) + (k & 3)] = gw3[i];
  }
  for (int i = tid; i < 640; i += 768) w4s[i] = gw4[i];
  __syncthreads();

  const int lane = tid & 63;
  const int wv = tid >> 6;
  const int gwv = blockIdx.x * WAVES + wv;

  const int s32 = lane & 31;
  const int s4w = lane & 3;
  const float4* __restrict__ r1a = reinterpret_cast<const float4*>(w1s + (lane << 4));
  const float4* __restrict__ r1b = reinterpret_cast<const float4*>(w1s + ((64 + lane) << 4));
  const float4* __restrict__ r2a = reinterpret_cast<const float4*>(w2s + (lane << 7));
  const float4* __restrict__ r2b = reinterpret_cast<const float4*>(w2s + ((64 + lane) << 7));
  const float4* __restrict__ r3  = reinterpret_cast<const float4*>(w3s + (lane << 7));
  const float*  __restrict__ r4f = w4s + ((lane < 10 ? lane : 0) << 6);

  float* __restrict__ spw = &spkf[wv][0][0];                 // per-wave spike buf
  const float4* __restrict__ spr = reinterpret_cast<const float4*>(spw);

  for (int grp = gwv; grp < NGRP; grp += TOTW) {
    const int bg = grp << 3;  // base batch index

    float m1a[S], m1b[S], m2a[S], m2b[S], m3v[S], m4v[S];
#pragma unroll
    for (int s = 0; s < S; ++s) {
      m1a[s] = 0.f; m1b[s] = 0.f; m2a[s] = 0.f; m2b[s] = 0.f; m3v[s] = 0.f; m4v[s] = 0.f;
    }

    for (int t = 0; t < kT; ++t) {
      const float4* __restrict__ xbase =
          reinterpret_cast<const float4*>(x + ((size_t)t * kB + bg) * 16);

      // ---------------- layer 1: dense fmaf, weights amortized over S
      float ca[S], cb[S];
#pragma unroll
      for (int s = 0; s < S; ++s) { ca[s] = 0.f; cb[s] = 0.f; }
#pragma unroll
      for (int c = 0; c < 4; ++c) {
        float4 wa = r1a[c ^ s4w];
        float4 wb = r1b[c ^ s4w];
#pragma unroll
        for (int s = 0; s < S; ++s) {
          float4 xs = xbase[(s << 2) + c];  // uniform-address load, cache-hit
          ca[s] = fma4(xs, wa, ca[s]);
          cb[s] = fma4(xs, wb, cb[s]);
        }
      }
#pragma unroll
      for (int s = 0; s < S; ++s) {
        float rs = m1a[s] > 1.0f ? 1.0f : 0.0f;
        m1a[s] = (0.9f * m1a[s] + ca[s]) - rs;
        float sa = m1a[s] > 1.0f ? 1.0f : 0.0f;
        float rs2 = m1b[s] > 1.0f ? 1.0f : 0.0f;
        m1b[s] = (0.9f * m1b[s] + cb[s]) - rs2;
        float sb = m1b[s] > 1.0f ? 1.0f : 0.0f;
        spw[(s << 7) + lane] = sa;        // spk1 floats, neuron `lane`
        spw[(s << 7) + 64 + lane] = sb;   // neuron 64+lane
      }

      // ---------------- layer 2: dense fma, spike float4 broadcast per (s,k4)
      float aa[S], ab[S];
#pragma unroll
      for (int s = 0; s < S; ++s) { aa[s] = 0.f; ab[s] = 0.f; }
#pragma unroll 4
      for (int k4 = 0; k4 < 32; ++k4) {
        float4 wa = r2a[k4 ^ s32];
        float4 wb = r2b[k4 ^ s32];
#pragma unroll
        for (int s = 0; s < S; ++s) {
          float4 sv = spr[(s << 5) + k4];   // uniform addr: broadcast, no conflict
          aa[s] = fma4(sv, wa, aa[s]);
          ab[s] = fma4(sv, wb, ab[s]);
        }
      }
#pragma unroll
      for (int s = 0; s < S; ++s) {
        float rs = m2a[s] > 1.0f ? 1.0f : 0.0f;
        m2a[s] = (0.9f * m2a[s] + aa[s]) - rs;
        float sa = m2a[s] > 1.0f ? 1.0f : 0.0f;
        float rs2 = m2b[s] > 1.0f ? 1.0f : 0.0f;
        m2b[s] = (0.9f * m2b[s] + ab[s]) - rs2;
        float sb = m2b[s] > 1.0f ? 1.0f : 0.0f;
        spw[(s << 7) + lane] = sa;        // overwrite with spk2 (spk1 consumed)
        spw[(s << 7) + 64 + lane] = sb;
      }

      // ---------------- layer 3: dense fma (d2 too high for skip to pay)
      float a3[S];
#pragma unroll
      for (int s = 0; s < S; ++s) a3[s] = 0.f;
#pragma unroll 4
      for (int k4 = 0; k4 < 32; ++k4) {
        float4 wc = r3[k4 ^ s32];
#pragma unroll
        for (int s = 0; s < S; ++s) {
          float4 sv = spr[(s << 5) + k4];
          a3[s] = fma4(sv, wc, a3[s]);
        }
      }

      // ---------------- LIF3 + layer 4 (very sparse: ballot + ctz) + out
#pragma unroll
      for (int s = 0; s < S; ++s) {
        float rs = m3v[s] > 1.0f ? 1.0f : 0.0f;
        m3v[s] = (0.9f * m3v[s] + a3[s]) - rs;
        unsigned long long mE = __ballot(m3v[s] > 1.0f);  // spk3 bits (64 neurons)
        float a4 = 0.f;
        while (mE) {  // ascending-k set-bit iteration (exact chain order)
          int k = __builtin_ctzll(mE);
          mE &= mE - 1;
          a4 += r4f[k];
        }
        float rs4 = m4v[s] > 1.0f ? 1.0f : 0.0f;
        m4v[s] = (0.9f * m4v[s] + a4) - rs4;
        float s4v = m4v[s] > 1.0f ? 1.0f : 0.0f;
        if (lane < 10) out[((size_t)t * kB + bg + s) * 10 + lane] = s4v;
      }
    }
  }
}

extern "C" void kernel_launch(void* const* d_in, const int* in_sizes, int n_in,
                              void* d_out, int out_size, void* d_ws, size_t ws_size,
                              hipStream_t stream) {
  const float* x   = (const float*)d_in[0];
  const float* w1  = (const float*)d_in[1];
  const float* w2  = (const float*)d_in[2];
  const float* w3  = (const float*)d_in[3];
  const float* w4  = (const float*)d_in[4];
  float* out = (float*)d_out;
  snn_fwd<<<dim3(256), dim3(768), 0, stream>>>(x, w1, w2, w3, w4, out);
}